// Round 11
// baseline (465.983 us; speedup 1.0000x reference)
//
#include <hip/hip_runtime.h>
#include <hip/hip_fp16.h>

// Exact-binned COO segment-sum, SUB-bucket-major (9-bit key), single-u32
// payload, fp16 x, deterministic slot assignment:
//   key = row >> 12  (489 keys of 4096 rows)
//   payload = (float_bits(p) & ~4095) | (row & 4095)   (12-bit row, 20-bit p)
//
// Pipeline (4 stream ops):
//   countchunks : one block per 4096-nnz chunk: rows -> 512-bin LDS hist ->
//                 counts row (u16); x->fp16 convert folded in; block 0 zeroes ctrl
//   scan        : one block per key: column of counts -> per-chunk prefix
//                 gstart[c][key] + key totals; LAST block scans totals -> starts
//   phaseA      : per-chunk: loads early (nt streams), lgkm-only barriers,
//                 512-bin LDS counting sort, deterministic dst (no atomics),
//                 nt run-flush into key-major g_w
//   phaseB      : one 1024-thr block per key: region read ONCE (uint4 nt),
//                 16KB LDS accumulate, fused proj + inf-norm; LAST block -> out
//
// ctrl (u32[2048], zeroed by countchunks block 0):
//   [0..511] totals | [512..1024] starts (513) | [1025..1026] maxslots |
//   [1027] done_scan | [1028] done_phaseB
// ws: ctrl 8KB | xh fp16[n] | counts u16[NC*512] | gstart u32[NC*512] |
//     g_w u32[nnz]   (~99 MB)

#define CHUNK 4096
#define KEYW 4096
#define NKEYS 512
#define KPT 16
#define SCAN_PER 20   // supports NC <= 5120 (nnz <= 20.97M)

typedef int   int4v   __attribute__((ext_vector_type(4)));
typedef float float4v __attribute__((ext_vector_type(4)));
typedef unsigned int uint4v __attribute__((ext_vector_type(4)));

#define LBAR() do { \
    asm volatile("s_waitcnt lgkmcnt(0)" ::: "memory"); \
    __builtin_amdgcn_s_barrier(); \
    asm volatile("" ::: "memory"); \
} while (0)

__global__ __launch_bounds__(256) void countchunks_kernel(
    const int* __restrict__ rows, const float* __restrict__ x,
    __half* __restrict__ xh, unsigned short* __restrict__ counts,
    unsigned int* __restrict__ ctrl, int nnz, int n)
{
    __shared__ unsigned int lh[NKEYS];
    const int t = threadIdx.x;
    lh[t] = 0u; lh[t + 256] = 0u;

    if (blockIdx.x == 0) {
        #pragma unroll
        for (int k = 0; k < 8; ++k) ctrl[t + 256 * k] = 0u;
    }

    // ---- x -> fp16 convert, grid-stride over whole grid ----
    {
        int tid = blockIdx.x * 256 + t;
        int stride = gridDim.x * 256;
        int n8 = n >> 3;
        const float4v* x4 = (const float4v*)x;
        uint4v* out4 = (uint4v*)xh;
        for (int i = tid; i < n8; i += stride) {
            float4v a = __builtin_nontemporal_load(&x4[i * 2]);
            float4v b = __builtin_nontemporal_load(&x4[i * 2 + 1]);
            __half2 h0 = __floats2half2_rn(a.x, a.y);
            __half2 h1 = __floats2half2_rn(a.z, a.w);
            __half2 h2 = __floats2half2_rn(b.x, b.y);
            __half2 h3 = __floats2half2_rn(b.z, b.w);
            uint4v o;
            o.x = *reinterpret_cast<unsigned int*>(&h0);
            o.y = *reinterpret_cast<unsigned int*>(&h1);
            o.z = *reinterpret_cast<unsigned int*>(&h2);
            o.w = *reinterpret_cast<unsigned int*>(&h3);
            out4[i] = o;
        }
        if (tid == 0)
            for (int i = n8 << 3; i < n; ++i) xh[i] = __float2half(x[i]);
    }
    __syncthreads();

    // ---- per-chunk 512-bin histogram ----
    const long base = (long)blockIdx.x * CHUNK;
    const int cnt = (int)min((long)CHUNK, (long)nnz - base);
    if (cnt == CHUNK) {
        const int4v* r4 = (const int4v*)(rows + base);
        #pragma unroll
        for (int k4 = 0; k4 < 4; ++k4) {
            int4v r = __builtin_nontemporal_load(&r4[t + 256 * k4]);
            atomicAdd(&lh[(unsigned)r.x >> 12], 1u);
            atomicAdd(&lh[(unsigned)r.y >> 12], 1u);
            atomicAdd(&lh[(unsigned)r.z >> 12], 1u);
            atomicAdd(&lh[(unsigned)r.w >> 12], 1u);
        }
    } else {
        #pragma unroll
        for (int k = 0; k < KPT; ++k) {
            int idx = (t + 256 * (k >> 2)) * 4 + (k & 3);
            if (idx < cnt) atomicAdd(&lh[(unsigned)rows[base + idx] >> 12], 1u);
        }
    }
    __syncthreads();
    counts[(size_t)blockIdx.x * NKEYS + t] = (unsigned short)lh[t];
    counts[(size_t)blockIdx.x * NKEYS + t + 256] = (unsigned short)lh[t + 256];
}

__global__ __launch_bounds__(256) void scan_kernel(
    const unsigned short* __restrict__ counts, unsigned int* __restrict__ gstart,
    unsigned int* __restrict__ ctrl, int NC)
{
    __shared__ unsigned int wsum[4];
    __shared__ unsigned int isLast;
    const int bk = blockIdx.x;
    const int t = threadIdx.x;

    // my 20-element segment of this key's column
    unsigned int lc[SCAN_PER];
    unsigned int s = 0;
    const int lo = t * SCAN_PER;
    #pragma unroll
    for (int k = 0; k < SCAN_PER; ++k) {
        int i = lo + k;
        lc[k] = (i < NC) ? (unsigned int)counts[(size_t)i * NKEYS + bk] : 0u;
        s += lc[k];
    }
    unsigned int inc = s;
    #pragma unroll
    for (int off = 1; off < 64; off <<= 1) {
        unsigned int nsh = __shfl_up(inc, off, 64);
        if ((t & 63) >= off) inc += nsh;
    }
    if ((t & 63) == 63) wsum[t >> 6] = inc;
    __syncthreads();
    unsigned int add = 0;
    for (int i = 0; i < (t >> 6); ++i) add += wsum[i];
    unsigned int run = inc - s + add;
    #pragma unroll
    for (int k = 0; k < SCAN_PER; ++k) {
        int i = lo + k;
        if (i < NC) { gstart[(size_t)i * NKEYS + bk] = run; run += lc[k]; }
    }
    if (t == 255) atomicAdd(&ctrl[bk], inc + add);   // key total
    __threadfence();
    if (t == 0) isLast = (atomicAdd(&ctrl[1027], 1u) == gridDim.x - 1) ? 1u : 0u;
    __syncthreads();
    if (isLast) {
        // pair-scan of 512 totals -> starts[513]
        unsigned int v0 = atomicAdd(&ctrl[2 * t], 0u);
        unsigned int v1 = atomicAdd(&ctrl[2 * t + 1], 0u);
        unsigned int s2 = v0 + v1;
        unsigned int inc2 = s2;
        #pragma unroll
        for (int off = 1; off < 64; off <<= 1) {
            unsigned int nsh = __shfl_up(inc2, off, 64);
            if ((t & 63) >= off) inc2 += nsh;
        }
        if ((t & 63) == 63) wsum[t >> 6] = inc2;
        __syncthreads();
        unsigned int add2 = 0;
        for (int i = 0; i < (t >> 6); ++i) add2 += wsum[i];
        unsigned int excl = inc2 - s2 + add2;
        ctrl[512 + 2 * t] = excl;
        ctrl[512 + 2 * t + 1] = excl + v0;
        if (t == 255) ctrl[512 + 512] = excl + v0 + v1;  // grand total
    }
}

__global__ __launch_bounds__(256) void phaseA_kernel(
    const float* __restrict__ vals, const int* __restrict__ rows,
    const int* __restrict__ cols, const __half* __restrict__ xh,
    const unsigned int* __restrict__ ctrl, const unsigned int* __restrict__ gstart,
    unsigned int* __restrict__ g_w, int nnz)
{
    __shared__ unsigned int wL[CHUNK];        // 16 KB packed payload
    __shared__ unsigned short bL[CHUNK];      // 8 KB key per slot
    __shared__ unsigned int hist[NKEYS];      // 2 KB
    __shared__ unsigned int cursor[NKEYS];    // 2 KB
    __shared__ int gstartI[NKEYS];            // 2 KB
    __shared__ unsigned int wsum[4];

    const int t = threadIdx.x;
    const long base = (long)blockIdx.x * CHUNK;
    const int cnt = (int)min((long)CHUNK, (long)nnz - base);
    const bool full = (cnt == CHUNK);

    hist[t] = 0u; hist[t + 256] = 0u;
    LBAR();

    // ---- issue all loads early: cols -> rows -> 16 xh-gathers -> vals ----
    int cc[KPT]; int rr[KPT]; __half xv[KPT]; float vv[KPT];
    if (full) {
        const int4v* c4 = (const int4v*)(cols + base);
        #pragma unroll
        for (int k4 = 0; k4 < 4; ++k4) {
            int4v c = __builtin_nontemporal_load(&c4[t + 256 * k4]);
            cc[k4 * 4 + 0] = c.x; cc[k4 * 4 + 1] = c.y;
            cc[k4 * 4 + 2] = c.z; cc[k4 * 4 + 3] = c.w;
        }
        const int4v* rows4 = (const int4v*)(rows + base);
        #pragma unroll
        for (int k4 = 0; k4 < 4; ++k4) {
            int4v r = __builtin_nontemporal_load(&rows4[t + 256 * k4]);
            rr[k4 * 4 + 0] = r.x; rr[k4 * 4 + 1] = r.y;
            rr[k4 * 4 + 2] = r.z; rr[k4 * 4 + 3] = r.w;
        }
        #pragma unroll
        for (int k = 0; k < KPT; ++k) xv[k] = xh[cc[k]];   // 16 L2-hit gathers
        const float4v* v4 = (const float4v*)(vals + base);
        #pragma unroll
        for (int k4 = 0; k4 < 4; ++k4) {
            float4v a = __builtin_nontemporal_load(&v4[t + 256 * k4]);
            vv[k4 * 4 + 0] = a.x; vv[k4 * 4 + 1] = a.y;
            vv[k4 * 4 + 2] = a.z; vv[k4 * 4 + 3] = a.w;
        }
    } else {
        #pragma unroll
        for (int k4 = 0; k4 < 4; ++k4)
            #pragma unroll
            for (int j = 0; j < 4; ++j) {
                int idx = (t + 256 * k4) * 4 + j;
                int k = k4 * 4 + j;
                if (idx < cnt) { cc[k] = cols[base + idx]; rr[k] = rows[base + idx]; vv[k] = vals[base + idx]; }
                else { cc[k] = 0; rr[k] = -1; vv[k] = 0.f; }
            }
        #pragma unroll
        for (int k = 0; k < KPT; ++k) xv[k] = xh[cc[k]];
    }

    // ---- histogram (consumes rr only; gathers + vals stay in flight) ----
    #pragma unroll
    for (int k = 0; k < KPT; ++k)
        if (rr[k] >= 0) atomicAdd(&hist[(unsigned)rr[k] >> 12], 1u);
    LBAR();

    // ---- pair-scan over 512 bins; deterministic dst base (NO atomics) ----
    unsigned int v0 = hist[2 * t];
    unsigned int v1 = hist[2 * t + 1];
    unsigned int s2 = v0 + v1;
    unsigned int inc = s2;
    #pragma unroll
    for (int off = 1; off < 64; off <<= 1) {
        unsigned int nsh = __shfl_up(inc, off, 64);
        if ((t & 63) >= off) inc += nsh;
    }
    if ((t & 63) == 63) wsum[t >> 6] = inc;
    LBAR();
    unsigned int add = 0;
    for (int i = 0; i < (t >> 6); ++i) add += wsum[i];
    unsigned int e0 = inc - s2 + add;        // exclusive prefix for bin 2t
    unsigned int e1 = e0 + v0;               // bin 2t+1
    cursor[2 * t] = e0;
    cursor[2 * t + 1] = e1;
    unsigned int gb0 = ctrl[512 + 2 * t] + gstart[(size_t)blockIdx.x * NKEYS + 2 * t];
    unsigned int gb1 = ctrl[512 + 2 * t + 1] + gstart[(size_t)blockIdx.x * NKEYS + 2 * t + 1];
    gstartI[2 * t] = (int)gb0 - (int)e0;
    gstartI[2 * t + 1] = (int)gb1 - (int)e1;
    LBAR();

    // ---- pack: p = val*x[col], stage sorted-by-key in LDS ----
    #pragma unroll
    for (int k = 0; k < KPT; ++k) {
        int r = rr[k];
        if (r >= 0) {
            float p = vv[k] * __half2float(xv[k]);
            unsigned int bk = (unsigned)r >> 12;
            unsigned int pos = atomicAdd(&cursor[bk], 1u);
            wL[pos] = (__float_as_uint(p) & ~4095u) | ((unsigned)r & 4095u);
            bL[pos] = (unsigned short)bk;
        }
    }
    LBAR();

    // ---- run-structured coalesced nt flush into key-major regions ----
    #pragma unroll
    for (int k = 0; k < KPT; ++k) {
        int i = t + 256 * k;
        if (i < cnt) {
            unsigned int bk = bL[i];
            __builtin_nontemporal_store(wL[i], &g_w[gstartI[bk] + i]);
        }
    }
}

__global__ __launch_bounds__(1024) void phaseB_kernel(
    unsigned int* __restrict__ ctrl,
    const unsigned int* __restrict__ g_w,
    const float* __restrict__ bvec, const float* __restrict__ iy,
    int m, float* __restrict__ out)
{
    __shared__ float accum[KEYW];   // 16 KB
    __shared__ float smp[16], smb[16];
    __shared__ unsigned int isLast;
    unsigned int* maxslots = ctrl + 1025;
    const int t = threadIdx.x;
    const int key = blockIdx.x;

    #pragma unroll
    for (int i = t; i < KEYW; i += 1024) accum[i] = 0.f;
    __syncthreads();

    const unsigned int s = ctrl[512 + key], e = ctrl[512 + key + 1];
    // head peel to 16B alignment
    unsigned int loA = (s + 3u) & ~3u;
    if (loA > e) loA = e;
    if (s + t < loA) {
        unsigned int w = g_w[s + t];
        atomicAdd(&accum[w & 4095u], __uint_as_float(w & ~4095u));
    }
    const unsigned int nvec = (e - loA) >> 2;
    const unsigned int e4 = loA + (nvec << 2);
    const uint4v* g4 = (const uint4v*)g_w;
    unsigned int k = (loA >> 2) + t;
    const unsigned int kend = (loA >> 2) + nvec;
    #define ACC(w) atomicAdd(&accum[(w) & 4095u], __uint_as_float((w) & ~4095u))
    for (; k + 3u * 1024u < kend; k += 4u * 1024u) {
        uint4v a = __builtin_nontemporal_load(&g4[k]);
        uint4v b = __builtin_nontemporal_load(&g4[k + 1024u]);
        uint4v c = __builtin_nontemporal_load(&g4[k + 2048u]);
        uint4v d = __builtin_nontemporal_load(&g4[k + 3072u]);
        ACC(a.x); ACC(a.y); ACC(a.z); ACC(a.w);
        ACC(b.x); ACC(b.y); ACC(b.z); ACC(b.w);
        ACC(c.x); ACC(c.y); ACC(c.z); ACC(c.w);
        ACC(d.x); ACC(d.y); ACC(d.z); ACC(d.w);
    }
    for (; k < kend; k += 1024u) {
        uint4v a = __builtin_nontemporal_load(&g4[k]);
        ACC(a.x); ACC(a.y); ACC(a.z); ACC(a.w);
    }
    #undef ACC
    if (e4 + t < e) {
        unsigned int w = g_w[e4 + t];
        atomicAdd(&accum[w & 4095u], __uint_as_float(w & ~4095u));
    }
    __syncthreads();

    // fused projection + inf-norm partial reduce (Ax stays in LDS)
    float mp = 0.f, mb = 0.f;
    long rb = (long)key * KEYW;
    #pragma unroll
    for (int i = t; i < KEYW; i += 1024) {
        long row = rb + i;
        if (row < m) {
            float a = accum[i];
            float bb = bvec[row];
            float y = a - bb;
            float pr = y + iy[row] * fmaxf(-y, 0.f);
            mp = fmaxf(mp, fabsf(pr));
            mb = fmaxf(mb, fabsf(bb));
        }
    }
    #pragma unroll
    for (int off = 32; off > 0; off >>= 1) {
        mp = fmaxf(mp, __shfl_down(mp, off, 64));
        mb = fmaxf(mb, __shfl_down(mb, off, 64));
    }
    if ((t & 63) == 0) { smp[t >> 6] = mp; smb[t >> 6] = mb; }
    __syncthreads();
    if (t == 0) {
        #pragma unroll
        for (int w = 1; w < 16; ++w) { mp = fmaxf(mp, smp[w]); mb = fmaxf(mb, smb[w]); }
        atomicMax(&maxslots[0], __float_as_uint(mp));
        atomicMax(&maxslots[1], __float_as_uint(mb));
        __threadfence();
        isLast = (atomicAdd(&ctrl[1028], 1u) == gridDim.x - 1) ? 1u : 0u;
    }
    __syncthreads();
    if (isLast && t == 0) {
        float p2 = __uint_as_float(atomicMax(&maxslots[0], 0u));
        float p3 = 1.f + __uint_as_float(atomicMax(&maxslots[1], 0u));
        out[0] = p2 / p3;
    }
}

// ---------- fallback path (tiny ws): direct scatter + reduce ----------
__global__ void fb_zero_kernel(float* __restrict__ ax, unsigned int* __restrict__ maxslots, int m) {
    int tid = blockIdx.x * blockDim.x + threadIdx.x;
    int stride = gridDim.x * blockDim.x;
    int m4 = m >> 2;
    float4* ax4 = reinterpret_cast<float4*>(ax);
    float4 z = make_float4(0.f, 0.f, 0.f, 0.f);
    for (int i = tid; i < m4; i += stride) ax4[i] = z;
    if (tid == 0) {
        for (int j = m4 << 2; j < m; ++j) ax[j] = 0.f;
        maxslots[0] = 0u; maxslots[1] = 0u;
    }
}

__global__ void fb_scatter_kernel(const float* __restrict__ vals, const int* __restrict__ rows,
                                  const int* __restrict__ cols, const float* __restrict__ x,
                                  float* __restrict__ ax, int nnz) {
    int i = (blockIdx.x * blockDim.x + threadIdx.x) << 2;
    if (i + 3 < nnz) {
        float4 v = *reinterpret_cast<const float4*>(vals + i);
        int4 r = *reinterpret_cast<const int4*>(rows + i);
        int4 c = *reinterpret_cast<const int4*>(cols + i);
        atomicAdd(&ax[r.x], v.x * x[c.x]);
        atomicAdd(&ax[r.y], v.y * x[c.y]);
        atomicAdd(&ax[r.z], v.z * x[c.z]);
        atomicAdd(&ax[r.w], v.w * x[c.w]);
    } else {
        for (; i < nnz; ++i) atomicAdd(&ax[rows[i]], vals[i] * x[cols[i]]);
    }
}

__global__ void fb_reduce_kernel(const float* __restrict__ ax, const float* __restrict__ b,
                                 const float* __restrict__ iy, unsigned int* __restrict__ maxslots, int m) {
    float mp = 0.f, mb = 0.f;
    int tid = blockIdx.x * blockDim.x + threadIdx.x;
    int stride = gridDim.x * blockDim.x;
    for (int i = tid; i < m; i += stride) {
        float bb = b[i];
        float y = ax[i] - bb;
        float p = y + iy[i] * fmaxf(-y, 0.f);
        mp = fmaxf(mp, fabsf(p));
        mb = fmaxf(mb, fabsf(bb));
    }
    #pragma unroll
    for (int off = 32; off > 0; off >>= 1) {
        mp = fmaxf(mp, __shfl_down(mp, off, 64));
        mb = fmaxf(mb, __shfl_down(mb, off, 64));
    }
    __shared__ float smp[4], smb[4];
    int wave = threadIdx.x >> 6;
    if ((threadIdx.x & 63) == 0) { smp[wave] = mp; smb[wave] = mb; }
    __syncthreads();
    if (threadIdx.x == 0) {
        for (int w = 1; w < (int)(blockDim.x >> 6); ++w) { mp = fmaxf(mp, smp[w]); mb = fmaxf(mb, smb[w]); }
        atomicMax(&maxslots[0], __float_as_uint(mp));
        atomicMax(&maxslots[1], __float_as_uint(mb));
    }
}

__global__ void fb_finalize_kernel(const unsigned int* __restrict__ maxslots, float* __restrict__ out) {
    if (threadIdx.x == 0 && blockIdx.x == 0) {
        float part2 = __uint_as_float(maxslots[0]);
        float part3 = 1.f + __uint_as_float(maxslots[1]);
        out[0] = part2 / part3;
    }
}

extern "C" void kernel_launch(void* const* d_in, const int* in_sizes, int n_in,
                              void* d_out, int out_size, void* d_ws, size_t ws_size,
                              hipStream_t stream) {
    const float* A_vals = (const float*)d_in[0];
    const float* b      = (const float*)d_in[1];
    // d_in[2] = c : unused
    const float* x      = (const float*)d_in[3];
    const float* Iy     = (const float*)d_in[4];
    const int* A_rows   = (const int*)d_in[5];
    const int* A_cols   = (const int*)d_in[6];

    int nnz = in_sizes[0];
    int m   = in_sizes[1];
    int n   = in_sizes[3];

    const int NC   = (nnz + CHUNK - 1) / CHUNK;
    const int NKEY = (m + KEYW - 1) / KEYW;

    auto al = [](size_t v) { return (v + 255) & ~(size_t)255; };
    size_t ctrlBytes = 8192;
    size_t xhOff     = al(ctrlBytes);
    size_t countsOff = al(xhOff + (size_t)n * 2);
    size_t gstartOff = al(countsOff + (size_t)NC * NKEYS * 2);
    size_t wOff      = al(gstartOff + (size_t)NC * NKEYS * 4);
    size_t need      = wOff + (size_t)nnz * 4;

    float* out = (float*)d_out;

    if (need <= ws_size && NKEY <= NKEYS - 1 && NC <= 256 * SCAN_PER && nnz >= 4 && n >= 8) {
        unsigned int* ctrl     = (unsigned int*)d_ws;
        __half* xh             = (__half*)((char*)d_ws + xhOff);
        unsigned short* counts = (unsigned short*)((char*)d_ws + countsOff);
        unsigned int* gstart   = (unsigned int*)((char*)d_ws + gstartOff);
        unsigned int* g_w      = (unsigned int*)((char*)d_ws + wOff);

        countchunks_kernel<<<NC, 256, 0, stream>>>(A_rows, x, xh, counts, ctrl, nnz, n);
        scan_kernel<<<NKEYS, 256, 0, stream>>>(counts, gstart, ctrl, NC);
        phaseA_kernel<<<NC, 256, 0, stream>>>(A_vals, A_rows, A_cols, xh, ctrl, gstart, g_w, nnz);
        phaseB_kernel<<<NKEY, 1024, 0, stream>>>(ctrl, g_w, b, Iy, m, out);
    } else {
        float* ax = (float*)d_ws;
        unsigned int* maxslots = (unsigned int*)(ax + m);
        fb_zero_kernel<<<2048, 256, 0, stream>>>(ax, maxslots, m);
        int nthreads = (nnz + 3) >> 2;
        fb_scatter_kernel<<<(nthreads + 255) / 256, 256, 0, stream>>>(A_vals, A_rows, A_cols, x, ax, nnz);
        fb_reduce_kernel<<<2048, 256, 0, stream>>>(ax, b, Iy, maxslots, m);
        fb_finalize_kernel<<<1, 64, 0, stream>>>(maxslots, out);
    }
}

// Round 12
// 284.268 us; speedup vs baseline: 1.6392x; 1.6392x over previous
//
#include <hip/hip_runtime.h>
#include <hip/hip_fp16.h>

// Exact-binned COO segment-sum, bucket-major with PADDED fixed regions,
// single-u32 payload, fp16 x:
//   payload = (float_bits(p) & ~8191) | (local_row & 8191), bucket = row>>13
//   bucket region = [bkt*PAD, bkt*PAD + ctr[bkt])  -- no precount/scan needed
//
// Pipeline (3 stream ops):
//   setup   : block 0 zeroes ctrl (4KB); all blocks convert x -> xh fp16
//   phaseA  : per-4096-nnz chunk: issue cols/rows/16 xh-gathers/vals early
//             (nt stream loads), lgkm-only barriers; 256-bin LDS counting
//             sort; slot reservation via per-bucket atomic counter into the
//             padded region; nt coalesced run-flush into g_w
//   phaseB  : TWO blocks per bucket split by row-half (bit 12 of local row):
//             each reads the bucket region (uint4, plain loads -> L3 reuse),
//             accumulates its half into 16KB LDS, fused proj + inf-norm;
//             LAST block writes out
//
// ctrl (u32[1024]): [0..255] bucket counters | [256..257] maxslots |
//                   [258] done_phaseB
// ws: ctrl 4KB | xh fp16[n] | g_w u32[nbuckets*PAD]   (~95 MB)

#define CHUNK 4096
#define BUCKW 8192
#define KPT 16

typedef int   int4v   __attribute__((ext_vector_type(4)));
typedef float float4v __attribute__((ext_vector_type(4)));
typedef unsigned int uint4v __attribute__((ext_vector_type(4)));

#define LBAR() do { \
    asm volatile("s_waitcnt lgkmcnt(0)" ::: "memory"); \
    __builtin_amdgcn_s_barrier(); \
    asm volatile("" ::: "memory"); \
} while (0)

__global__ __launch_bounds__(256) void setup_kernel(
    const float* __restrict__ x, __half* __restrict__ xh,
    unsigned int* __restrict__ ctrl, int n)
{
    const int t = threadIdx.x;
    if (blockIdx.x == 0) {
        #pragma unroll
        for (int k = 0; k < 4; ++k) ctrl[t + 256 * k] = 0u;
    }
    int tid = blockIdx.x * 256 + t;
    int stride = gridDim.x * 256;
    int n8 = n >> 3;
    const float4v* x4 = (const float4v*)x;
    uint4v* out4 = (uint4v*)xh;
    for (int i = tid; i < n8; i += stride) {
        float4v a = __builtin_nontemporal_load(&x4[i * 2]);
        float4v b = __builtin_nontemporal_load(&x4[i * 2 + 1]);
        __half2 h0 = __floats2half2_rn(a.x, a.y);
        __half2 h1 = __floats2half2_rn(a.z, a.w);
        __half2 h2 = __floats2half2_rn(b.x, b.y);
        __half2 h3 = __floats2half2_rn(b.z, b.w);
        uint4v o;
        o.x = *reinterpret_cast<unsigned int*>(&h0);
        o.y = *reinterpret_cast<unsigned int*>(&h1);
        o.z = *reinterpret_cast<unsigned int*>(&h2);
        o.w = *reinterpret_cast<unsigned int*>(&h3);
        out4[i] = o;
    }
    if (tid == 0)
        for (int i = n8 << 3; i < n; ++i) xh[i] = __float2half(x[i]);
}

__global__ __launch_bounds__(256) void phaseA_kernel(
    const float* __restrict__ vals, const int* __restrict__ rows,
    const int* __restrict__ cols, const __half* __restrict__ xh,
    unsigned int* __restrict__ ctrl,
    unsigned int* __restrict__ g_w, int nnz, unsigned int pad)
{
    __shared__ unsigned int wL[CHUNK];        // 16 KB packed payload
    __shared__ unsigned char bL[CHUNK];       // 4 KB bucket id
    __shared__ unsigned int hist[256], cursor[256];
    __shared__ int gstartI[256];
    __shared__ unsigned int wsum[4];

    const int t = threadIdx.x;
    const long base = (long)blockIdx.x * CHUNK;
    const int cnt = (int)min((long)CHUNK, (long)nnz - base);
    const bool full = (cnt == CHUNK);

    hist[t] = 0u;
    LBAR();

    // ---- issue all loads early: cols -> rows -> 16 xh-gathers -> vals ----
    int cc[KPT]; int rr[KPT]; __half xv[KPT]; float vv[KPT];
    if (full) {
        const int4v* c4 = (const int4v*)(cols + base);
        #pragma unroll
        for (int k4 = 0; k4 < 4; ++k4) {
            int4v c = __builtin_nontemporal_load(&c4[t + 256 * k4]);
            cc[k4 * 4 + 0] = c.x; cc[k4 * 4 + 1] = c.y;
            cc[k4 * 4 + 2] = c.z; cc[k4 * 4 + 3] = c.w;
        }
        const int4v* rows4 = (const int4v*)(rows + base);
        #pragma unroll
        for (int k4 = 0; k4 < 4; ++k4) {
            int4v r = __builtin_nontemporal_load(&rows4[t + 256 * k4]);
            rr[k4 * 4 + 0] = r.x; rr[k4 * 4 + 1] = r.y;
            rr[k4 * 4 + 2] = r.z; rr[k4 * 4 + 3] = r.w;
        }
        #pragma unroll
        for (int k = 0; k < KPT; ++k) xv[k] = xh[cc[k]];   // 16 L2-hit gathers
        const float4v* v4 = (const float4v*)(vals + base);
        #pragma unroll
        for (int k4 = 0; k4 < 4; ++k4) {
            float4v a = __builtin_nontemporal_load(&v4[t + 256 * k4]);
            vv[k4 * 4 + 0] = a.x; vv[k4 * 4 + 1] = a.y;
            vv[k4 * 4 + 2] = a.z; vv[k4 * 4 + 3] = a.w;
        }
    } else {
        #pragma unroll
        for (int k4 = 0; k4 < 4; ++k4)
            #pragma unroll
            for (int j = 0; j < 4; ++j) {
                int idx = (t + 256 * k4) * 4 + j;
                int k = k4 * 4 + j;
                if (idx < cnt) { cc[k] = cols[base + idx]; rr[k] = rows[base + idx]; vv[k] = vals[base + idx]; }
                else { cc[k] = 0; rr[k] = -1; vv[k] = 0.f; }
            }
        #pragma unroll
        for (int k = 0; k < KPT; ++k) xv[k] = xh[cc[k]];
    }

    // ---- histogram (consumes rr only; gathers + vals stay in flight) ----
    #pragma unroll
    for (int k = 0; k < KPT; ++k)
        if (rr[k] >= 0) atomicAdd(&hist[(unsigned)rr[k] >> 13], 1u);
    LBAR();

    // ---- chunk-local exclusive scan + padded-region slot reservation ----
    unsigned int v = hist[t];
    unsigned int inc = v;
    #pragma unroll
    for (int off = 1; off < 64; off <<= 1) {
        unsigned int nsh = __shfl_up(inc, off, 64);
        if ((t & 63) >= off) inc += nsh;
    }
    if ((t & 63) == 63) wsum[t >> 6] = inc;
    LBAR();
    unsigned int add = 0;
    for (int i = 0; i < (t >> 6); ++i) add += wsum[i];
    unsigned int excl = inc - v + add;
    cursor[t] = excl;
    unsigned int gb = (unsigned)t * pad + (v ? atomicAdd(&ctrl[t], v) : 0u);
    gstartI[t] = (int)gb - (int)excl;
    LBAR();

    // ---- pack: p = val*x[col], stage sorted-by-bucket in LDS ----
    #pragma unroll
    for (int k = 0; k < KPT; ++k) {
        int r = rr[k];
        if (r >= 0) {
            float p = vv[k] * __half2float(xv[k]);
            unsigned int bk = (unsigned)r >> 13;
            unsigned int pos = atomicAdd(&cursor[bk], 1u);
            wL[pos] = (__float_as_uint(p) & ~8191u) | ((unsigned)r & 8191u);
            bL[pos] = (unsigned char)bk;
        }
    }
    LBAR();

    // ---- run-structured coalesced nt flush into padded bucket regions ----
    #pragma unroll
    for (int k = 0; k < KPT; ++k) {
        int i = t + 256 * k;
        if (i < cnt) {
            unsigned int bk = bL[i];
            __builtin_nontemporal_store(wL[i], &g_w[gstartI[bk] + i]);
        }
    }
}

__global__ __launch_bounds__(1024) void phaseB_kernel(
    unsigned int* __restrict__ ctrl,
    const unsigned int* __restrict__ g_w,
    const float* __restrict__ bvec, const float* __restrict__ iy,
    int m, unsigned int pad, float* __restrict__ out)
{
    __shared__ float accum[BUCKW / 2];   // 16 KB (one row-half)
    __shared__ float smp[16], smb[16];
    __shared__ unsigned int isLast;
    unsigned int* maxslots = ctrl + 256;
    const int t = threadIdx.x;
    const int bkt = blockIdx.x >> 1;
    const unsigned int h = blockIdx.x & 1;          // row-half selector
    const unsigned int keepbit = h << 12;           // bit 12 of local row

    #pragma unroll
    for (int i = t; i < BUCKW / 2; i += 1024) accum[i] = 0.f;
    __syncthreads();

    const unsigned int s = (unsigned)bkt * pad;
    const unsigned int e = s + ctrl[bkt];
    // s is 16B-aligned (pad % 4 == 0)
    const unsigned int nvec = (e - s) >> 2;
    const unsigned int e4 = s + (nvec << 2);
    const uint4v* g4 = (const uint4v*)g_w;
    unsigned int k = (s >> 2) + t;
    const unsigned int kend = (s >> 2) + nvec;
    #define ACC(w) if (((w) & 4096u) == keepbit) atomicAdd(&accum[(w) & 4095u], __uint_as_float((w) & ~8191u))
    for (; k + 3u * 1024u < kend; k += 4u * 1024u) {
        uint4v a = g4[k];
        uint4v b = g4[k + 1024u];
        uint4v c = g4[k + 2048u];
        uint4v d = g4[k + 3072u];
        ACC(a.x); ACC(a.y); ACC(a.z); ACC(a.w);
        ACC(b.x); ACC(b.y); ACC(b.z); ACC(b.w);
        ACC(c.x); ACC(c.y); ACC(c.z); ACC(c.w);
        ACC(d.x); ACC(d.y); ACC(d.z); ACC(d.w);
    }
    for (; k < kend; k += 1024u) {
        uint4v a = g4[k];
        ACC(a.x); ACC(a.y); ACC(a.z); ACC(a.w);
    }
    #undef ACC
    if (e4 + t < e) {
        unsigned int w = g_w[e4 + t];
        if ((w & 4096u) == keepbit)
            atomicAdd(&accum[w & 4095u], __uint_as_float(w & ~8191u));
    }
    __syncthreads();

    // fused projection + inf-norm partial reduce on this row half
    float mp = 0.f, mb = 0.f;
    long rb = (long)bkt * BUCKW + (long)h * (BUCKW / 2);
    #pragma unroll
    for (int i = t; i < BUCKW / 2; i += 1024) {
        long row = rb + i;
        if (row < m) {
            float a = accum[i];
            float bb = bvec[row];
            float y = a - bb;
            float pr = y + iy[row] * fmaxf(-y, 0.f);
            mp = fmaxf(mp, fabsf(pr));
            mb = fmaxf(mb, fabsf(bb));
        }
    }
    #pragma unroll
    for (int off = 32; off > 0; off >>= 1) {
        mp = fmaxf(mp, __shfl_down(mp, off, 64));
        mb = fmaxf(mb, __shfl_down(mb, off, 64));
    }
    if ((t & 63) == 0) { smp[t >> 6] = mp; smb[t >> 6] = mb; }
    __syncthreads();
    if (t == 0) {
        #pragma unroll
        for (int w = 1; w < 16; ++w) { mp = fmaxf(mp, smp[w]); mb = fmaxf(mb, smb[w]); }
        atomicMax(&maxslots[0], __float_as_uint(mp));
        atomicMax(&maxslots[1], __float_as_uint(mb));
        __threadfence();
        isLast = (atomicAdd(&ctrl[258], 1u) == gridDim.x - 1) ? 1u : 0u;
    }
    __syncthreads();
    if (isLast && t == 0) {
        float p2 = __uint_as_float(atomicMax(&maxslots[0], 0u));
        float p3 = 1.f + __uint_as_float(atomicMax(&maxslots[1], 0u));
        out[0] = p2 / p3;
    }
}

// ---------- fallback path (tiny ws): direct scatter + reduce ----------
__global__ void fb_zero_kernel(float* __restrict__ ax, unsigned int* __restrict__ maxslots, int m) {
    int tid = blockIdx.x * blockDim.x + threadIdx.x;
    int stride = gridDim.x * blockDim.x;
    int m4 = m >> 2;
    float4* ax4 = reinterpret_cast<float4*>(ax);
    float4 z = make_float4(0.f, 0.f, 0.f, 0.f);
    for (int i = tid; i < m4; i += stride) ax4[i] = z;
    if (tid == 0) {
        for (int j = m4 << 2; j < m; ++j) ax[j] = 0.f;
        maxslots[0] = 0u; maxslots[1] = 0u;
    }
}

__global__ void fb_scatter_kernel(const float* __restrict__ vals, const int* __restrict__ rows,
                                  const int* __restrict__ cols, const float* __restrict__ x,
                                  float* __restrict__ ax, int nnz) {
    int i = (blockIdx.x * blockDim.x + threadIdx.x) << 2;
    if (i + 3 < nnz) {
        float4 v = *reinterpret_cast<const float4*>(vals + i);
        int4 r = *reinterpret_cast<const int4*>(rows + i);
        int4 c = *reinterpret_cast<const int4*>(cols + i);
        atomicAdd(&ax[r.x], v.x * x[c.x]);
        atomicAdd(&ax[r.y], v.y * x[c.y]);
        atomicAdd(&ax[r.z], v.z * x[c.z]);
        atomicAdd(&ax[r.w], v.w * x[c.w]);
    } else {
        for (; i < nnz; ++i) atomicAdd(&ax[rows[i]], vals[i] * x[cols[i]]);
    }
}

__global__ void fb_reduce_kernel(const float* __restrict__ ax, const float* __restrict__ b,
                                 const float* __restrict__ iy, unsigned int* __restrict__ maxslots, int m) {
    float mp = 0.f, mb = 0.f;
    int tid = blockIdx.x * blockDim.x + threadIdx.x;
    int stride = gridDim.x * blockDim.x;
    for (int i = tid; i < m; i += stride) {
        float bb = b[i];
        float y = ax[i] - bb;
        float p = y + iy[i] * fmaxf(-y, 0.f);
        mp = fmaxf(mp, fabsf(p));
        mb = fmaxf(mb, fabsf(bb));
    }
    #pragma unroll
    for (int off = 32; off > 0; off >>= 1) {
        mp = fmaxf(mp, __shfl_down(mp, off, 64));
        mb = fmaxf(mb, __shfl_down(mb, off, 64));
    }
    __shared__ float smp[4], smb[4];
    int wave = threadIdx.x >> 6;
    if ((threadIdx.x & 63) == 0) { smp[wave] = mp; smb[wave] = mb; }
    __syncthreads();
    if (threadIdx.x == 0) {
        for (int w = 1; w < (int)(blockDim.x >> 6); ++w) { mp = fmaxf(mp, smp[w]); mb = fmaxf(mb, smb[w]); }
        atomicMax(&maxslots[0], __float_as_uint(mp));
        atomicMax(&maxslots[1], __float_as_uint(mb));
    }
}

__global__ void fb_finalize_kernel(const unsigned int* __restrict__ maxslots, float* __restrict__ out) {
    if (threadIdx.x == 0 && blockIdx.x == 0) {
        float part2 = __uint_as_float(maxslots[0]);
        float part3 = 1.f + __uint_as_float(maxslots[1]);
        out[0] = part2 / part3;
    }
}

extern "C" void kernel_launch(void* const* d_in, const int* in_sizes, int n_in,
                              void* d_out, int out_size, void* d_ws, size_t ws_size,
                              hipStream_t stream) {
    const float* A_vals = (const float*)d_in[0];
    const float* b      = (const float*)d_in[1];
    // d_in[2] = c : unused
    const float* x      = (const float*)d_in[3];
    const float* Iy     = (const float*)d_in[4];
    const int* A_rows   = (const int*)d_in[5];
    const int* A_cols   = (const int*)d_in[6];

    int nnz = in_sizes[0];
    int m   = in_sizes[1];
    int n   = in_sizes[3];

    const int NC = (nnz + CHUNK - 1) / CHUNK;
    const int NB = (m + BUCKW - 1) / BUCKW;

    // padded per-bucket region: mean + max(mean/8, 8192), 16B-aligned
    unsigned int mean = (NB > 0) ? (unsigned int)((long)nnz / NB) : 0u;
    unsigned int slack = mean / 8u; if (slack < 8192u) slack = 8192u;
    unsigned int pad = (mean + slack + CHUNK + 3u) & ~3u;   // +CHUNK guards worst-case chunk skew

    auto al = [](size_t v) { return (v + 255) & ~(size_t)255; };
    size_t ctrlBytes = 4096;
    size_t xhOff = al(ctrlBytes);
    size_t wOff  = al(xhOff + (size_t)n * 2);
    size_t need  = wOff + (size_t)NB * pad * 4;

    float* out = (float*)d_out;

    if (need <= ws_size && NB <= 255 && nnz >= 4 && n >= 8) {
        unsigned int* ctrl = (unsigned int*)d_ws;
        __half* xh         = (__half*)((char*)d_ws + xhOff);
        unsigned int* g_w  = (unsigned int*)((char*)d_ws + wOff);

        setup_kernel<<<977, 256, 0, stream>>>(x, xh, ctrl, n);
        phaseA_kernel<<<NC, 256, 0, stream>>>(A_vals, A_rows, A_cols, xh, ctrl, g_w, nnz, pad);
        phaseB_kernel<<<NB * 2, 1024, 0, stream>>>(ctrl, g_w, b, Iy, m, pad, out);
    } else {
        float* ax = (float*)d_ws;
        unsigned int* maxslots = (unsigned int*)(ax + m);
        fb_zero_kernel<<<2048, 256, 0, stream>>>(ax, maxslots, m);
        int nthreads = (nnz + 3) >> 2;
        fb_scatter_kernel<<<(nthreads + 255) / 256, 256, 0, stream>>>(A_vals, A_rows, A_cols, x, ax, nnz);
        fb_reduce_kernel<<<2048, 256, 0, stream>>>(ax, b, Iy, maxslots, m);
        fb_finalize_kernel<<<1, 64, 0, stream>>>(maxslots, out);
    }
}

// Round 13
// 280.204 us; speedup vs baseline: 1.6630x; 1.0145x over previous
//
#include <hip/hip_runtime.h>
#include <hip/hip_fp16.h>

// Exact-binned COO segment-sum, bucket-major with PADDED fixed regions,
// single-u32 payload, fp16 x:
//   payload = (float_bits(p) & ~8191) | (local_row & 8191), bucket = row>>13
//   bucket region = [bkt*PAD, bkt*PAD + ctr[bkt])
//
// Pipeline (4 stream ops):
//   setup    : block 0 zeroes ctrl (1KB counters); all blocks convert x->xh fp16
//   phaseA   : per-4096-nnz chunk: loads early (nt streams), lgkm-only
//              barriers; 256-bin LDS counting sort; padded-region slot
//              reservation (per-bucket atomic); nt run-flush into g_w
//   phaseB   : TWO blocks per bucket split by row-half (bit 12): region read
//              (uint4), 16KB LDS accumulate, fused proj + inf-norm;
//              partial maxes -> PRIVATE slots (NO threadfence, NO atomicMax,
//              NO done-counter -- fence was the suspected hidden cost)
//   finalize : 1 block reduces the 2*NB partial pairs -> out
//
// ctrl (u32[256]): bucket counters
// ws: ctrl 4KB | pmax f32[2048] | xh fp16[n] | g_w u32[NB*PAD]

#define CHUNK 4096
#define BUCKW 8192
#define KPT 16

typedef int   int4v   __attribute__((ext_vector_type(4)));
typedef float float4v __attribute__((ext_vector_type(4)));
typedef unsigned int uint4v __attribute__((ext_vector_type(4)));

#define LBAR() do { \
    asm volatile("s_waitcnt lgkmcnt(0)" ::: "memory"); \
    __builtin_amdgcn_s_barrier(); \
    asm volatile("" ::: "memory"); \
} while (0)

__global__ __launch_bounds__(256) void setup_kernel(
    const float* __restrict__ x, __half* __restrict__ xh,
    unsigned int* __restrict__ ctrl, int n)
{
    const int t = threadIdx.x;
    if (blockIdx.x == 0) ctrl[t] = 0u;
    int tid = blockIdx.x * 256 + t;
    int stride = gridDim.x * 256;
    int n8 = n >> 3;
    const float4v* x4 = (const float4v*)x;
    uint4v* out4 = (uint4v*)xh;
    for (int i = tid; i < n8; i += stride) {
        float4v a = __builtin_nontemporal_load(&x4[i * 2]);
        float4v b = __builtin_nontemporal_load(&x4[i * 2 + 1]);
        __half2 h0 = __floats2half2_rn(a.x, a.y);
        __half2 h1 = __floats2half2_rn(a.z, a.w);
        __half2 h2 = __floats2half2_rn(b.x, b.y);
        __half2 h3 = __floats2half2_rn(b.z, b.w);
        uint4v o;
        o.x = *reinterpret_cast<unsigned int*>(&h0);
        o.y = *reinterpret_cast<unsigned int*>(&h1);
        o.z = *reinterpret_cast<unsigned int*>(&h2);
        o.w = *reinterpret_cast<unsigned int*>(&h3);
        out4[i] = o;
    }
    if (tid == 0)
        for (int i = n8 << 3; i < n; ++i) xh[i] = __float2half(x[i]);
}

__global__ __launch_bounds__(256) void phaseA_kernel(
    const float* __restrict__ vals, const int* __restrict__ rows,
    const int* __restrict__ cols, const __half* __restrict__ xh,
    unsigned int* __restrict__ ctrl,
    unsigned int* __restrict__ g_w, int nnz, unsigned int pad)
{
    __shared__ unsigned int wL[CHUNK];        // 16 KB packed payload
    __shared__ unsigned char bL[CHUNK];       // 4 KB bucket id
    __shared__ unsigned int hist[256], cursor[256];
    __shared__ int gstartI[256];
    __shared__ unsigned int wsum[4];

    const int t = threadIdx.x;
    const long base = (long)blockIdx.x * CHUNK;
    const int cnt = (int)min((long)CHUNK, (long)nnz - base);
    const bool full = (cnt == CHUNK);

    hist[t] = 0u;
    LBAR();

    // ---- issue all loads early: cols -> rows -> 16 xh-gathers -> vals ----
    int cc[KPT]; int rr[KPT]; __half xv[KPT]; float vv[KPT];
    if (full) {
        const int4v* c4 = (const int4v*)(cols + base);
        #pragma unroll
        for (int k4 = 0; k4 < 4; ++k4) {
            int4v c = __builtin_nontemporal_load(&c4[t + 256 * k4]);
            cc[k4 * 4 + 0] = c.x; cc[k4 * 4 + 1] = c.y;
            cc[k4 * 4 + 2] = c.z; cc[k4 * 4 + 3] = c.w;
        }
        const int4v* rows4 = (const int4v*)(rows + base);
        #pragma unroll
        for (int k4 = 0; k4 < 4; ++k4) {
            int4v r = __builtin_nontemporal_load(&rows4[t + 256 * k4]);
            rr[k4 * 4 + 0] = r.x; rr[k4 * 4 + 1] = r.y;
            rr[k4 * 4 + 2] = r.z; rr[k4 * 4 + 3] = r.w;
        }
        #pragma unroll
        for (int k = 0; k < KPT; ++k) xv[k] = xh[cc[k]];   // 16 L2-hit gathers
        const float4v* v4 = (const float4v*)(vals + base);
        #pragma unroll
        for (int k4 = 0; k4 < 4; ++k4) {
            float4v a = __builtin_nontemporal_load(&v4[t + 256 * k4]);
            vv[k4 * 4 + 0] = a.x; vv[k4 * 4 + 1] = a.y;
            vv[k4 * 4 + 2] = a.z; vv[k4 * 4 + 3] = a.w;
        }
    } else {
        #pragma unroll
        for (int k4 = 0; k4 < 4; ++k4)
            #pragma unroll
            for (int j = 0; j < 4; ++j) {
                int idx = (t + 256 * k4) * 4 + j;
                int k = k4 * 4 + j;
                if (idx < cnt) { cc[k] = cols[base + idx]; rr[k] = rows[base + idx]; vv[k] = vals[base + idx]; }
                else { cc[k] = 0; rr[k] = -1; vv[k] = 0.f; }
            }
        #pragma unroll
        for (int k = 0; k < KPT; ++k) xv[k] = xh[cc[k]];
    }

    // ---- histogram (consumes rr only; gathers + vals stay in flight) ----
    #pragma unroll
    for (int k = 0; k < KPT; ++k)
        if (rr[k] >= 0) atomicAdd(&hist[(unsigned)rr[k] >> 13], 1u);
    LBAR();

    // ---- chunk-local exclusive scan + padded-region slot reservation ----
    unsigned int v = hist[t];
    unsigned int inc = v;
    #pragma unroll
    for (int off = 1; off < 64; off <<= 1) {
        unsigned int nsh = __shfl_up(inc, off, 64);
        if ((t & 63) >= off) inc += nsh;
    }
    if ((t & 63) == 63) wsum[t >> 6] = inc;
    LBAR();
    unsigned int add = 0;
    for (int i = 0; i < (t >> 6); ++i) add += wsum[i];
    unsigned int excl = inc - v + add;
    cursor[t] = excl;
    unsigned int gb = (unsigned)t * pad + (v ? atomicAdd(&ctrl[t], v) : 0u);
    gstartI[t] = (int)gb - (int)excl;
    LBAR();

    // ---- pack: p = val*x[col], stage sorted-by-bucket in LDS ----
    #pragma unroll
    for (int k = 0; k < KPT; ++k) {
        int r = rr[k];
        if (r >= 0) {
            float p = vv[k] * __half2float(xv[k]);
            unsigned int bk = (unsigned)r >> 13;
            unsigned int pos = atomicAdd(&cursor[bk], 1u);
            wL[pos] = (__float_as_uint(p) & ~8191u) | ((unsigned)r & 8191u);
            bL[pos] = (unsigned char)bk;
        }
    }
    LBAR();

    // ---- run-structured coalesced nt flush into padded bucket regions ----
    #pragma unroll
    for (int k = 0; k < KPT; ++k) {
        int i = t + 256 * k;
        if (i < cnt) {
            unsigned int bk = bL[i];
            __builtin_nontemporal_store(wL[i], &g_w[gstartI[bk] + i]);
        }
    }
}

__global__ __launch_bounds__(1024) void phaseB_kernel(
    const unsigned int* __restrict__ ctrl,
    const unsigned int* __restrict__ g_w,
    const float* __restrict__ bvec, const float* __restrict__ iy,
    int m, unsigned int pad, float* __restrict__ pmax)
{
    __shared__ float accum[BUCKW / 2];   // 16 KB (one row-half)
    __shared__ float smp[16], smb[16];
    const int t = threadIdx.x;
    const int bkt = blockIdx.x >> 1;
    const unsigned int h = blockIdx.x & 1;          // row-half selector
    const unsigned int keepbit = h << 12;           // bit 12 of local row

    #pragma unroll
    for (int i = t; i < BUCKW / 2; i += 1024) accum[i] = 0.f;
    __syncthreads();

    const unsigned int s = (unsigned)bkt * pad;
    const unsigned int e = s + ctrl[bkt];
    const unsigned int nvec = (e - s) >> 2;      // s is 16B-aligned
    const unsigned int e4 = s + (nvec << 2);
    const uint4v* g4 = (const uint4v*)g_w;
    unsigned int k = (s >> 2) + t;
    const unsigned int kend = (s >> 2) + nvec;
    #define ACC(w) if (((w) & 4096u) == keepbit) atomicAdd(&accum[(w) & 4095u], __uint_as_float((w) & ~8191u))
    for (; k + 3u * 1024u < kend; k += 4u * 1024u) {
        uint4v a = g4[k];
        uint4v b = g4[k + 1024u];
        uint4v c = g4[k + 2048u];
        uint4v d = g4[k + 3072u];
        ACC(a.x); ACC(a.y); ACC(a.z); ACC(a.w);
        ACC(b.x); ACC(b.y); ACC(b.z); ACC(b.w);
        ACC(c.x); ACC(c.y); ACC(c.z); ACC(c.w);
        ACC(d.x); ACC(d.y); ACC(d.z); ACC(d.w);
    }
    for (; k < kend; k += 1024u) {
        uint4v a = g4[k];
        ACC(a.x); ACC(a.y); ACC(a.z); ACC(a.w);
    }
    #undef ACC
    if (e4 + t < e) {
        unsigned int w = g_w[e4 + t];
        if ((w & 4096u) == keepbit)
            atomicAdd(&accum[w & 4095u], __uint_as_float(w & ~8191u));
    }
    __syncthreads();

    // fused projection + inf-norm partial reduce on this row half
    float mp = 0.f, mb = 0.f;
    long rb = (long)bkt * BUCKW + (long)h * (BUCKW / 2);
    #pragma unroll
    for (int i = t; i < BUCKW / 2; i += 1024) {
        long row = rb + i;
        if (row < m) {
            float a = accum[i];
            float bb = bvec[row];
            float y = a - bb;
            float pr = y + iy[row] * fmaxf(-y, 0.f);
            mp = fmaxf(mp, fabsf(pr));
            mb = fmaxf(mb, fabsf(bb));
        }
    }
    #pragma unroll
    for (int off = 32; off > 0; off >>= 1) {
        mp = fmaxf(mp, __shfl_down(mp, off, 64));
        mb = fmaxf(mb, __shfl_down(mb, off, 64));
    }
    if ((t & 63) == 0) { smp[t >> 6] = mp; smb[t >> 6] = mb; }
    __syncthreads();
    if (t == 0) {
        #pragma unroll
        for (int w = 1; w < 16; ++w) { mp = fmaxf(mp, smp[w]); mb = fmaxf(mb, smb[w]); }
        // private slots: NO fence, NO atomics, NO done-counter
        pmax[blockIdx.x] = mp;
        pmax[1024 + blockIdx.x] = mb;
    }
}

__global__ __launch_bounds__(256) void finalize_kernel(
    const float* __restrict__ pmax, int nb2, float* __restrict__ out)
{
    __shared__ float smp[4], smb[4];
    const int t = threadIdx.x;
    float mp = 0.f, mb = 0.f;
    for (int i = t; i < nb2; i += 256) {
        mp = fmaxf(mp, pmax[i]);
        mb = fmaxf(mb, pmax[1024 + i]);
    }
    #pragma unroll
    for (int off = 32; off > 0; off >>= 1) {
        mp = fmaxf(mp, __shfl_down(mp, off, 64));
        mb = fmaxf(mb, __shfl_down(mb, off, 64));
    }
    if ((t & 63) == 0) { smp[t >> 6] = mp; smb[t >> 6] = mb; }
    __syncthreads();
    if (t == 0) {
        #pragma unroll
        for (int w = 1; w < 4; ++w) { mp = fmaxf(mp, smp[w]); mb = fmaxf(mb, smb[w]); }
        out[0] = mp / (1.f + mb);
    }
}

// ---------- fallback path (tiny ws): direct scatter + reduce ----------
__global__ void fb_zero_kernel(float* __restrict__ ax, unsigned int* __restrict__ maxslots, int m) {
    int tid = blockIdx.x * blockDim.x + threadIdx.x;
    int stride = gridDim.x * blockDim.x;
    int m4 = m >> 2;
    float4* ax4 = reinterpret_cast<float4*>(ax);
    float4 z = make_float4(0.f, 0.f, 0.f, 0.f);
    for (int i = tid; i < m4; i += stride) ax4[i] = z;
    if (tid == 0) {
        for (int j = m4 << 2; j < m; ++j) ax[j] = 0.f;
        maxslots[0] = 0u; maxslots[1] = 0u;
    }
}

__global__ void fb_scatter_kernel(const float* __restrict__ vals, const int* __restrict__ rows,
                                  const int* __restrict__ cols, const float* __restrict__ x,
                                  float* __restrict__ ax, int nnz) {
    int i = (blockIdx.x * blockDim.x + threadIdx.x) << 2;
    if (i + 3 < nnz) {
        float4 v = *reinterpret_cast<const float4*>(vals + i);
        int4 r = *reinterpret_cast<const int4*>(rows + i);
        int4 c = *reinterpret_cast<const int4*>(cols + i);
        atomicAdd(&ax[r.x], v.x * x[c.x]);
        atomicAdd(&ax[r.y], v.y * x[c.y]);
        atomicAdd(&ax[r.z], v.z * x[c.z]);
        atomicAdd(&ax[r.w], v.w * x[c.w]);
    } else {
        for (; i < nnz; ++i) atomicAdd(&ax[rows[i]], vals[i] * x[cols[i]]);
    }
}

__global__ void fb_reduce_kernel(const float* __restrict__ ax, const float* __restrict__ b,
                                 const float* __restrict__ iy, unsigned int* __restrict__ maxslots, int m) {
    float mp = 0.f, mb = 0.f;
    int tid = blockIdx.x * blockDim.x + threadIdx.x;
    int stride = gridDim.x * blockDim.x;
    for (int i = tid; i < m; i += stride) {
        float bb = b[i];
        float y = ax[i] - bb;
        float p = y + iy[i] * fmaxf(-y, 0.f);
        mp = fmaxf(mp, fabsf(p));
        mb = fmaxf(mb, fabsf(bb));
    }
    #pragma unroll
    for (int off = 32; off > 0; off >>= 1) {
        mp = fmaxf(mp, __shfl_down(mp, off, 64));
        mb = fmaxf(mb, __shfl_down(mb, off, 64));
    }
    __shared__ float smp[4], smb[4];
    int wave = threadIdx.x >> 6;
    if ((threadIdx.x & 63) == 0) { smp[wave] = mp; smb[wave] = mb; }
    __syncthreads();
    if (threadIdx.x == 0) {
        for (int w = 1; w < (int)(blockDim.x >> 6); ++w) { mp = fmaxf(mp, smp[w]); mb = fmaxf(mb, smb[w]); }
        atomicMax(&maxslots[0], __float_as_uint(mp));
        atomicMax(&maxslots[1], __float_as_uint(mb));
    }
}

__global__ void fb_finalize_kernel(const unsigned int* __restrict__ maxslots, float* __restrict__ out) {
    if (threadIdx.x == 0 && blockIdx.x == 0) {
        float part2 = __uint_as_float(maxslots[0]);
        float part3 = 1.f + __uint_as_float(maxslots[1]);
        out[0] = part2 / part3;
    }
}

extern "C" void kernel_launch(void* const* d_in, const int* in_sizes, int n_in,
                              void* d_out, int out_size, void* d_ws, size_t ws_size,
                              hipStream_t stream) {
    const float* A_vals = (const float*)d_in[0];
    const float* b      = (const float*)d_in[1];
    // d_in[2] = c : unused
    const float* x      = (const float*)d_in[3];
    const float* Iy     = (const float*)d_in[4];
    const int* A_rows   = (const int*)d_in[5];
    const int* A_cols   = (const int*)d_in[6];

    int nnz = in_sizes[0];
    int m   = in_sizes[1];
    int n   = in_sizes[3];

    const int NC = (nnz + CHUNK - 1) / CHUNK;
    const int NB = (m + BUCKW - 1) / BUCKW;

    // padded per-bucket region: mean + max(mean/8, 8192) + CHUNK, 16B-aligned
    unsigned int mean = (NB > 0) ? (unsigned int)((long)nnz / NB) : 0u;
    unsigned int slack = mean / 8u; if (slack < 8192u) slack = 8192u;
    unsigned int pad = (mean + slack + CHUNK + 3u) & ~3u;

    auto al = [](size_t v) { return (v + 255) & ~(size_t)255; };
    size_t ctrlBytes = 4096;
    size_t pmaxOff = al(ctrlBytes);
    size_t xhOff   = al(pmaxOff + 2048 * 4);
    size_t wOff    = al(xhOff + (size_t)n * 2);
    size_t need    = wOff + (size_t)NB * pad * 4;

    float* out = (float*)d_out;

    if (need <= ws_size && NB <= 255 && nnz >= 4 && n >= 8) {
        unsigned int* ctrl = (unsigned int*)d_ws;
        float* pmax        = (float*)((char*)d_ws + pmaxOff);
        __half* xh         = (__half*)((char*)d_ws + xhOff);
        unsigned int* g_w  = (unsigned int*)((char*)d_ws + wOff);

        setup_kernel<<<977, 256, 0, stream>>>(x, xh, ctrl, n);
        phaseA_kernel<<<NC, 256, 0, stream>>>(A_vals, A_rows, A_cols, xh, ctrl, g_w, nnz, pad);
        phaseB_kernel<<<NB * 2, 1024, 0, stream>>>(ctrl, g_w, b, Iy, m, pad, pmax);
        finalize_kernel<<<1, 256, 0, stream>>>(pmax, NB * 2, out);
    } else {
        float* ax = (float*)d_ws;
        unsigned int* maxslots = (unsigned int*)(ax + m);
        fb_zero_kernel<<<2048, 256, 0, stream>>>(ax, maxslots, m);
        int nthreads = (nnz + 3) >> 2;
        fb_scatter_kernel<<<(nthreads + 255) / 256, 256, 0, stream>>>(A_vals, A_rows, A_cols, x, ax, nnz);
        fb_reduce_kernel<<<2048, 256, 0, stream>>>(ax, b, Iy, maxslots, m);
        fb_finalize_kernel<<<1, 64, 0, stream>>>(maxslots, out);
    }
}

// Round 14
// 280.030 us; speedup vs baseline: 1.6640x; 1.0006x over previous
//
#include <hip/hip_runtime.h>
#include <hip/hip_fp16.h>

// Exact-binned COO segment-sum, bucket-major with PADDED fixed regions,
// single-u32 payload, fp16 x:
//   payload = (float_bits(p) & ~8191) | (local_row & 8191), bucket = row>>13
//   bucket region = [bkt*PAD, bkt*PAD + ctr[bkt])
//
// Pipeline (4 stream ops):
//   setup    : block 0 zeroes ctrl; all blocks convert x->xh fp16
//   phaseA   : per-4096-nnz chunk: loads early (nt streams), lgkm-only
//              barriers; 256-bin LDS counting sort; padded-region slot
//              reservation; nt run-flush into g_w
//   phaseB   : ONE 1024-thr block per bucket: region read ONCE (uint4,
//              8-deep MLP), full 32KB LDS accumulate (no filter), fused
//              proj + inf-norm; partial maxes -> private slots (no fence)
//   finalize : 1 block reduces NB partial pairs -> out
//
// ctrl (u32[256]): bucket counters
// ws: ctrl 4KB | pmax f32[2048] | xh fp16[n] | g_w u32[NB*PAD]

#define CHUNK 4096
#define BUCKW 8192
#define KPT 16

typedef int   int4v   __attribute__((ext_vector_type(4)));
typedef float float4v __attribute__((ext_vector_type(4)));
typedef unsigned int uint4v __attribute__((ext_vector_type(4)));

#define LBAR() do { \
    asm volatile("s_waitcnt lgkmcnt(0)" ::: "memory"); \
    __builtin_amdgcn_s_barrier(); \
    asm volatile("" ::: "memory"); \
} while (0)

__global__ __launch_bounds__(256) void setup_kernel(
    const float* __restrict__ x, __half* __restrict__ xh,
    unsigned int* __restrict__ ctrl, int n)
{
    const int t = threadIdx.x;
    if (blockIdx.x == 0) ctrl[t] = 0u;
    int tid = blockIdx.x * 256 + t;
    int stride = gridDim.x * 256;
    int n8 = n >> 3;
    const float4v* x4 = (const float4v*)x;
    uint4v* out4 = (uint4v*)xh;
    for (int i = tid; i < n8; i += stride) {
        float4v a = __builtin_nontemporal_load(&x4[i * 2]);
        float4v b = __builtin_nontemporal_load(&x4[i * 2 + 1]);
        __half2 h0 = __floats2half2_rn(a.x, a.y);
        __half2 h1 = __floats2half2_rn(a.z, a.w);
        __half2 h2 = __floats2half2_rn(b.x, b.y);
        __half2 h3 = __floats2half2_rn(b.z, b.w);
        uint4v o;
        o.x = *reinterpret_cast<unsigned int*>(&h0);
        o.y = *reinterpret_cast<unsigned int*>(&h1);
        o.z = *reinterpret_cast<unsigned int*>(&h2);
        o.w = *reinterpret_cast<unsigned int*>(&h3);
        out4[i] = o;
    }
    if (tid == 0)
        for (int i = n8 << 3; i < n; ++i) xh[i] = __float2half(x[i]);
}

__global__ __launch_bounds__(256) void phaseA_kernel(
    const float* __restrict__ vals, const int* __restrict__ rows,
    const int* __restrict__ cols, const __half* __restrict__ xh,
    unsigned int* __restrict__ ctrl,
    unsigned int* __restrict__ g_w, int nnz, unsigned int pad)
{
    __shared__ unsigned int wL[CHUNK];        // 16 KB packed payload
    __shared__ unsigned char bL[CHUNK];       // 4 KB bucket id
    __shared__ unsigned int hist[256], cursor[256];
    __shared__ int gstartI[256];
    __shared__ unsigned int wsum[4];

    const int t = threadIdx.x;
    const long base = (long)blockIdx.x * CHUNK;
    const int cnt = (int)min((long)CHUNK, (long)nnz - base);
    const bool full = (cnt == CHUNK);

    hist[t] = 0u;
    LBAR();

    // ---- issue all loads early: cols -> rows -> 16 xh-gathers -> vals ----
    int cc[KPT]; int rr[KPT]; __half xv[KPT]; float vv[KPT];
    if (full) {
        const int4v* c4 = (const int4v*)(cols + base);
        #pragma unroll
        for (int k4 = 0; k4 < 4; ++k4) {
            int4v c = __builtin_nontemporal_load(&c4[t + 256 * k4]);
            cc[k4 * 4 + 0] = c.x; cc[k4 * 4 + 1] = c.y;
            cc[k4 * 4 + 2] = c.z; cc[k4 * 4 + 3] = c.w;
        }
        const int4v* rows4 = (const int4v*)(rows + base);
        #pragma unroll
        for (int k4 = 0; k4 < 4; ++k4) {
            int4v r = __builtin_nontemporal_load(&rows4[t + 256 * k4]);
            rr[k4 * 4 + 0] = r.x; rr[k4 * 4 + 1] = r.y;
            rr[k4 * 4 + 2] = r.z; rr[k4 * 4 + 3] = r.w;
        }
        #pragma unroll
        for (int k = 0; k < KPT; ++k) xv[k] = xh[cc[k]];   // 16 L2-hit gathers
        const float4v* v4 = (const float4v*)(vals + base);
        #pragma unroll
        for (int k4 = 0; k4 < 4; ++k4) {
            float4v a = __builtin_nontemporal_load(&v4[t + 256 * k4]);
            vv[k4 * 4 + 0] = a.x; vv[k4 * 4 + 1] = a.y;
            vv[k4 * 4 + 2] = a.z; vv[k4 * 4 + 3] = a.w;
        }
    } else {
        #pragma unroll
        for (int k4 = 0; k4 < 4; ++k4)
            #pragma unroll
            for (int j = 0; j < 4; ++j) {
                int idx = (t + 256 * k4) * 4 + j;
                int k = k4 * 4 + j;
                if (idx < cnt) { cc[k] = cols[base + idx]; rr[k] = rows[base + idx]; vv[k] = vals[base + idx]; }
                else { cc[k] = 0; rr[k] = -1; vv[k] = 0.f; }
            }
        #pragma unroll
        for (int k = 0; k < KPT; ++k) xv[k] = xh[cc[k]];
    }

    // ---- histogram (consumes rr only; gathers + vals stay in flight) ----
    #pragma unroll
    for (int k = 0; k < KPT; ++k)
        if (rr[k] >= 0) atomicAdd(&hist[(unsigned)rr[k] >> 13], 1u);
    LBAR();

    // ---- chunk-local exclusive scan + padded-region slot reservation ----
    unsigned int v = hist[t];
    unsigned int inc = v;
    #pragma unroll
    for (int off = 1; off < 64; off <<= 1) {
        unsigned int nsh = __shfl_up(inc, off, 64);
        if ((t & 63) >= off) inc += nsh;
    }
    if ((t & 63) == 63) wsum[t >> 6] = inc;
    LBAR();
    unsigned int add = 0;
    for (int i = 0; i < (t >> 6); ++i) add += wsum[i];
    unsigned int excl = inc - v + add;
    cursor[t] = excl;
    unsigned int gb = (unsigned)t * pad + (v ? atomicAdd(&ctrl[t], v) : 0u);
    gstartI[t] = (int)gb - (int)excl;
    LBAR();

    // ---- pack: p = val*x[col], stage sorted-by-bucket in LDS ----
    #pragma unroll
    for (int k = 0; k < KPT; ++k) {
        int r = rr[k];
        if (r >= 0) {
            float p = vv[k] * __half2float(xv[k]);
            unsigned int bk = (unsigned)r >> 13;
            unsigned int pos = atomicAdd(&cursor[bk], 1u);
            wL[pos] = (__float_as_uint(p) & ~8191u) | ((unsigned)r & 8191u);
            bL[pos] = (unsigned char)bk;
        }
    }
    LBAR();

    // ---- run-structured coalesced nt flush into padded bucket regions ----
    #pragma unroll
    for (int k = 0; k < KPT; ++k) {
        int i = t + 256 * k;
        if (i < cnt) {
            unsigned int bk = bL[i];
            __builtin_nontemporal_store(wL[i], &g_w[gstartI[bk] + i]);
        }
    }
}

__global__ __launch_bounds__(1024) void phaseB_kernel(
    const unsigned int* __restrict__ ctrl,
    const unsigned int* __restrict__ g_w,
    const float* __restrict__ bvec, const float* __restrict__ iy,
    int m, unsigned int pad, float* __restrict__ pmax)
{
    __shared__ float accum[BUCKW];   // 32 KB (full bucket)
    __shared__ float smp[16], smb[16];
    const int t = threadIdx.x;
    const int bkt = blockIdx.x;

    #pragma unroll
    for (int i = t; i < BUCKW; i += 1024) accum[i] = 0.f;
    __syncthreads();

    const unsigned int s = (unsigned)bkt * pad;     // 16B-aligned
    const unsigned int e = s + ctrl[bkt];
    const unsigned int nvec = (e - s) >> 2;
    const unsigned int e4 = s + (nvec << 2);
    const uint4v* g4 = (const uint4v*)g_w;
    unsigned int k = (s >> 2) + t;
    const unsigned int kend = (s >> 2) + nvec;
    #define ACC(w) atomicAdd(&accum[(w) & 8191u], __uint_as_float((w) & ~8191u))
    // 8-deep MLP: 8 uint4 in flight per thread
    for (; k + 7u * 1024u < kend; k += 8u * 1024u) {
        uint4v a0 = g4[k];
        uint4v a1 = g4[k + 1024u];
        uint4v a2 = g4[k + 2048u];
        uint4v a3 = g4[k + 3072u];
        uint4v a4 = g4[k + 4096u];
        uint4v a5 = g4[k + 5120u];
        uint4v a6 = g4[k + 6144u];
        uint4v a7 = g4[k + 7168u];
        ACC(a0.x); ACC(a0.y); ACC(a0.z); ACC(a0.w);
        ACC(a1.x); ACC(a1.y); ACC(a1.z); ACC(a1.w);
        ACC(a2.x); ACC(a2.y); ACC(a2.z); ACC(a2.w);
        ACC(a3.x); ACC(a3.y); ACC(a3.z); ACC(a3.w);
        ACC(a4.x); ACC(a4.y); ACC(a4.z); ACC(a4.w);
        ACC(a5.x); ACC(a5.y); ACC(a5.z); ACC(a5.w);
        ACC(a6.x); ACC(a6.y); ACC(a6.z); ACC(a6.w);
        ACC(a7.x); ACC(a7.y); ACC(a7.z); ACC(a7.w);
    }
    for (; k < kend; k += 1024u) {
        uint4v a = g4[k];
        ACC(a.x); ACC(a.y); ACC(a.z); ACC(a.w);
    }
    #undef ACC
    if (e4 + t < e) {
        unsigned int w = g_w[e4 + t];
        atomicAdd(&accum[w & 8191u], __uint_as_float(w & ~8191u));
    }
    __syncthreads();

    // fused projection + inf-norm partial reduce (Ax stays in LDS)
    float mp = 0.f, mb = 0.f;
    long rb = (long)bkt * BUCKW;
    #pragma unroll
    for (int i = t; i < BUCKW; i += 1024) {
        long row = rb + i;
        if (row < m) {
            float a = accum[i];
            float bb = bvec[row];
            float y = a - bb;
            float pr = y + iy[row] * fmaxf(-y, 0.f);
            mp = fmaxf(mp, fabsf(pr));
            mb = fmaxf(mb, fabsf(bb));
        }
    }
    #pragma unroll
    for (int off = 32; off > 0; off >>= 1) {
        mp = fmaxf(mp, __shfl_down(mp, off, 64));
        mb = fmaxf(mb, __shfl_down(mb, off, 64));
    }
    if ((t & 63) == 0) { smp[t >> 6] = mp; smb[t >> 6] = mb; }
    __syncthreads();
    if (t == 0) {
        #pragma unroll
        for (int w = 1; w < 16; ++w) { mp = fmaxf(mp, smp[w]); mb = fmaxf(mb, smb[w]); }
        // private slots: no fence, no atomics, no done-counter
        pmax[blockIdx.x] = mp;
        pmax[1024 + blockIdx.x] = mb;
    }
}

__global__ __launch_bounds__(256) void finalize_kernel(
    const float* __restrict__ pmax, int nb, float* __restrict__ out)
{
    __shared__ float smp[4], smb[4];
    const int t = threadIdx.x;
    float mp = 0.f, mb = 0.f;
    for (int i = t; i < nb; i += 256) {
        mp = fmaxf(mp, pmax[i]);
        mb = fmaxf(mb, pmax[1024 + i]);
    }
    #pragma unroll
    for (int off = 32; off > 0; off >>= 1) {
        mp = fmaxf(mp, __shfl_down(mp, off, 64));
        mb = fmaxf(mb, __shfl_down(mb, off, 64));
    }
    if ((t & 63) == 0) { smp[t >> 6] = mp; smb[t >> 6] = mb; }
    __syncthreads();
    if (t == 0) {
        #pragma unroll
        for (int w = 1; w < 4; ++w) { mp = fmaxf(mp, smp[w]); mb = fmaxf(mb, smb[w]); }
        out[0] = mp / (1.f + mb);
    }
}

// ---------- fallback path (tiny ws): direct scatter + reduce ----------
__global__ void fb_zero_kernel(float* __restrict__ ax, unsigned int* __restrict__ maxslots, int m) {
    int tid = blockIdx.x * blockDim.x + threadIdx.x;
    int stride = gridDim.x * blockDim.x;
    int m4 = m >> 2;
    float4* ax4 = reinterpret_cast<float4*>(ax);
    float4 z = make_float4(0.f, 0.f, 0.f, 0.f);
    for (int i = tid; i < m4; i += stride) ax4[i] = z;
    if (tid == 0) {
        for (int j = m4 << 2; j < m; ++j) ax[j] = 0.f;
        maxslots[0] = 0u; maxslots[1] = 0u;
    }
}

__global__ void fb_scatter_kernel(const float* __restrict__ vals, const int* __restrict__ rows,
                                  const int* __restrict__ cols, const float* __restrict__ x,
                                  float* __restrict__ ax, int nnz) {
    int i = (blockIdx.x * blockDim.x + threadIdx.x) << 2;
    if (i + 3 < nnz) {
        float4 v = *reinterpret_cast<const float4*>(vals + i);
        int4 r = *reinterpret_cast<const int4*>(rows + i);
        int4 c = *reinterpret_cast<const int4*>(cols + i);
        atomicAdd(&ax[r.x], v.x * x[c.x]);
        atomicAdd(&ax[r.y], v.y * x[c.y]);
        atomicAdd(&ax[r.z], v.z * x[c.z]);
        atomicAdd(&ax[r.w], v.w * x[c.w]);
    } else {
        for (; i < nnz; ++i) atomicAdd(&ax[rows[i]], vals[i] * x[cols[i]]);
    }
}

__global__ void fb_reduce_kernel(const float* __restrict__ ax, const float* __restrict__ b,
                                 const float* __restrict__ iy, unsigned int* __restrict__ maxslots, int m) {
    float mp = 0.f, mb = 0.f;
    int tid = blockIdx.x * blockDim.x + threadIdx.x;
    int stride = gridDim.x * blockDim.x;
    for (int i = tid; i < m; i += stride) {
        float bb = b[i];
        float y = ax[i] - bb;
        float p = y + iy[i] * fmaxf(-y, 0.f);
        mp = fmaxf(mp, fabsf(p));
        mb = fmaxf(mb, fabsf(bb));
    }
    #pragma unroll
    for (int off = 32; off > 0; off >>= 1) {
        mp = fmaxf(mp, __shfl_down(mp, off, 64));
        mb = fmaxf(mb, __shfl_down(mb, off, 64));
    }
    __shared__ float smp[4], smb[4];
    int wave = threadIdx.x >> 6;
    if ((threadIdx.x & 63) == 0) { smp[wave] = mp; smb[wave] = mb; }
    __syncthreads();
    if (threadIdx.x == 0) {
        for (int w = 1; w < (int)(blockDim.x >> 6); ++w) { mp = fmaxf(mp, smp[w]); mb = fmaxf(mb, smb[w]); }
        atomicMax(&maxslots[0], __float_as_uint(mp));
        atomicMax(&maxslots[1], __float_as_uint(mb));
    }
}

__global__ void fb_finalize_kernel(const unsigned int* __restrict__ maxslots, float* __restrict__ out) {
    if (threadIdx.x == 0 && blockIdx.x == 0) {
        float part2 = __uint_as_float(maxslots[0]);
        float part3 = 1.f + __uint_as_float(maxslots[1]);
        out[0] = part2 / part3;
    }
}

extern "C" void kernel_launch(void* const* d_in, const int* in_sizes, int n_in,
                              void* d_out, int out_size, void* d_ws, size_t ws_size,
                              hipStream_t stream) {
    const float* A_vals = (const float*)d_in[0];
    const float* b      = (const float*)d_in[1];
    // d_in[2] = c : unused
    const float* x      = (const float*)d_in[3];
    const float* Iy     = (const float*)d_in[4];
    const int* A_rows   = (const int*)d_in[5];
    const int* A_cols   = (const int*)d_in[6];

    int nnz = in_sizes[0];
    int m   = in_sizes[1];
    int n   = in_sizes[3];

    const int NC = (nnz + CHUNK - 1) / CHUNK;
    const int NB = (m + BUCKW - 1) / BUCKW;

    // padded per-bucket region: mean + max(mean/8, 8192) + CHUNK, 16B-aligned
    unsigned int mean = (NB > 0) ? (unsigned int)((long)nnz / NB) : 0u;
    unsigned int slack = mean / 8u; if (slack < 8192u) slack = 8192u;
    unsigned int pad = (mean + slack + CHUNK + 3u) & ~3u;

    auto al = [](size_t v) { return (v + 255) & ~(size_t)255; };
    size_t ctrlBytes = 4096;
    size_t pmaxOff = al(ctrlBytes);
    size_t xhOff   = al(pmaxOff + 2048 * 4);
    size_t wOff    = al(xhOff + (size_t)n * 2);
    size_t need    = wOff + (size_t)NB * pad * 4;

    float* out = (float*)d_out;

    if (need <= ws_size && NB <= 255 && nnz >= 4 && n >= 8) {
        unsigned int* ctrl = (unsigned int*)d_ws;
        float* pmax        = (float*)((char*)d_ws + pmaxOff);
        __half* xh         = (__half*)((char*)d_ws + xhOff);
        unsigned int* g_w  = (unsigned int*)((char*)d_ws + wOff);

        setup_kernel<<<977, 256, 0, stream>>>(x, xh, ctrl, n);
        phaseA_kernel<<<NC, 256, 0, stream>>>(A_vals, A_rows, A_cols, xh, ctrl, g_w, nnz, pad);
        phaseB_kernel<<<NB, 1024, 0, stream>>>(ctrl, g_w, b, Iy, m, pad, pmax);
        finalize_kernel<<<1, 256, 0, stream>>>(pmax, NB, out);
    } else {
        float* ax = (float*)d_ws;
        unsigned int* maxslots = (unsigned int*)(ax + m);
        fb_zero_kernel<<<2048, 256, 0, stream>>>(ax, maxslots, m);
        int nthreads = (nnz + 3) >> 2;
        fb_scatter_kernel<<<(nthreads + 255) / 256, 256, 0, stream>>>(A_vals, A_rows, A_cols, x, ax, nnz);
        fb_reduce_kernel<<<2048, 256, 0, stream>>>(ax, b, Iy, maxslots, m);
        fb_finalize_kernel<<<1, 64, 0, stream>>>(maxslots, out);
    }
}